// Round 1
// baseline (229.290 us; speedup 1.0000x reference)
//
#include <hip/hip_runtime.h>
#include <hip/hip_bf16.h>

typedef unsigned short u16;
typedef short bf16x8 __attribute__((ext_vector_type(8)));
typedef float f32x4 __attribute__((ext_vector_type(4)));

#define S_LEN 2048
#define DQ 512
#define NBATCH 4

__device__ __forceinline__ u16 f2bf(float f) {
    __hip_bfloat16 h = __float2bfloat16(f);
    return *reinterpret_cast<u16*>(&h);
}

__device__ __forceinline__ void async16(const u16* g, u16* l) {
    __builtin_amdgcn_global_load_lds(
        (__attribute__((address_space(1))) void*)g,
        (__attribute__((address_space(3))) void*)l, 16, 0, 0);
}

// -------- fp32 -> bf16 convert (vectorized x4) --------
__global__ __launch_bounds__(256) void k_cvt(const float* __restrict__ in,
                                             u16* __restrict__ out, int n4) {
    int i = blockIdx.x * 256 + threadIdx.x;
    if (i < n4) {
        f32x4 v = *(const f32x4*)(in + (size_t)i * 4);
        ushort4 o;
        o.x = f2bf(v.x); o.y = f2bf(v.y); o.z = f2bf(v.z); o.w = f2bf(v.w);
        *(ushort4*)(out + (size_t)i * 4) = o;
    }
}

// -------- shared 128x128 GEMM core: C += A[128xK] * B[128xK]^T (both row-major, bf16) --------
// A,B pre-offset to the block's first row. LDS tiles 128x32 bf16 each.
__device__ __forceinline__ void gemm_core(const u16* __restrict__ A, const u16* __restrict__ B,
                                          int K, f32x4 acc[4][4], u16* ldsA, u16* ldsB, int tid) {
    const int lane = tid & 63;
    const int w    = tid >> 6;
    const int wm   = (w & 1) << 6;
    const int wn   = (w >> 1) << 6;
    const int l16  = lane & 15;
    const int quad = lane >> 4;

    for (int k0 = 0; k0 < K; k0 += 32) {
        // stage A,B tiles (128 rows x 32 cols bf16 = 8 KB each) via direct-to-LDS 16B loads
#pragma unroll
        for (int i = 0; i < 2; ++i) {
            int c  = i * 256 + tid;        // chunk 0..511, 16B each
            int r  = c >> 2;               // row 0..127
            int cc = (c & 3) << 3;         // col element 0/8/16/24
            async16(A + (size_t)r * K + k0 + cc, ldsA + r * 32 + cc);
            async16(B + (size_t)r * K + k0 + cc, ldsB + r * 32 + cc);
        }
        __syncthreads();
        bf16x8 af[4], bf[4];
#pragma unroll
        for (int i = 0; i < 4; ++i)
            af[i] = *(const bf16x8*)(ldsA + (wm + i * 16 + l16) * 32 + quad * 8);
#pragma unroll
        for (int j = 0; j < 4; ++j)
            bf[j] = *(const bf16x8*)(ldsB + (wn + j * 16 + l16) * 32 + quad * 8);
#pragma unroll
        for (int i = 0; i < 4; ++i)
#pragma unroll
            for (int j = 0; j < 4; ++j)
                acc[i][j] = __builtin_amdgcn_mfma_f32_16x16x32_bf16(af[i], bf[j], acc[i][j], 0, 0, 0);
        __syncthreads();
    }
}

// -------- projection: out(z) = x * W(z)^T + b(z), bf16 out; z in {Q,K,V} --------
__global__ __launch_bounds__(256) void k_proj(const u16* __restrict__ xb, const u16* __restrict__ Wb,
                                              const float* __restrict__ bq, const float* __restrict__ bk,
                                              const float* __restrict__ bv, u16* __restrict__ out) {
    __shared__ __align__(16) u16 lds[8192];
    const int z = blockIdx.z;
    const int m0 = blockIdx.y * 128, n0 = blockIdx.x * 128;
    const u16* A = xb + (size_t)m0 * DQ;
    const u16* B = Wb + (size_t)z * DQ * DQ + (size_t)n0 * DQ;
    const float* bias = (z == 0) ? bq : (z == 1) ? bk : bv;

    f32x4 acc[4][4];
#pragma unroll
    for (int i = 0; i < 4; ++i)
#pragma unroll
        for (int j = 0; j < 4; ++j) acc[i][j] = (f32x4)0.0f;

    int tid = threadIdx.x;
    gemm_core(A, B, DQ, acc, lds, lds + 4096, tid);

    const int lane = tid & 63, w = tid >> 6;
    const int wm = (w & 1) << 6, wn = (w >> 1) << 6;
    const int l16 = lane & 15, quad = lane >> 4;
    u16* outz = out + (size_t)z * 8192 * DQ;
#pragma unroll
    for (int j = 0; j < 4; ++j) {
        int gn = n0 + wn + j * 16 + l16;
        float bb = bias[gn];
#pragma unroll
        for (int i = 0; i < 4; ++i)
#pragma unroll
            for (int r = 0; r < 4; ++r) {
                int gm = m0 + wm + i * 16 + quad * 4 + r;
                outz[(size_t)gm * DQ + gn] = f2bf(acc[i][j][r] + bb);
            }
    }
}

// -------- V [2048x512] -> V^T [512x2048] per batch --------
__global__ __launch_bounds__(256) void k_transpose(const u16* __restrict__ V, u16* __restrict__ VT) {
    __shared__ u16 tile[32][33];
    const int b = blockIdx.z;
    const int t0 = blockIdx.x * 32, d0 = blockIdx.y * 32;
    const u16* Vb_ = V + (size_t)b * S_LEN * DQ;
    u16* VTb_ = VT + (size_t)b * DQ * S_LEN;
    const int tx = threadIdx.x & 31, ty = threadIdx.x >> 5;
#pragma unroll
    for (int r = 0; r < 4; ++r)
        tile[ty + r * 8][tx] = Vb_[(size_t)(t0 + ty + r * 8) * DQ + d0 + tx];
    __syncthreads();
#pragma unroll
    for (int r = 0; r < 4; ++r)
        VTb_[(size_t)(d0 + ty + r * 8) * S_LEN + t0 + tx] = tile[tx][ty + r * 8];
}

// -------- scores = Q K^T * scale, fp32 raw into d_out --------
__global__ __launch_bounds__(256) void k_scores(const u16* __restrict__ Qb, const u16* __restrict__ Kb,
                                                float* __restrict__ out) {
    __shared__ __align__(16) u16 lds[8192];
    const int b = blockIdx.z;
    const int m0 = blockIdx.y * 128, n0 = blockIdx.x * 128;
    const u16* A = Qb + ((size_t)b * S_LEN + m0) * DQ;
    const u16* B = Kb + ((size_t)b * S_LEN + n0) * DQ;

    f32x4 acc[4][4];
#pragma unroll
    for (int i = 0; i < 4; ++i)
#pragma unroll
        for (int j = 0; j < 4; ++j) acc[i][j] = (f32x4)0.0f;

    int tid = threadIdx.x;
    gemm_core(A, B, DQ, acc, lds, lds + 4096, tid);

    const float scale = 0.044194173824159216f; // 1/sqrt(512)
    const int lane = tid & 63, w = tid >> 6;
    const int wm = (w & 1) << 6, wn = (w >> 1) << 6;
    const int l16 = lane & 15, quad = lane >> 4;
    float* outb = out + (size_t)b * S_LEN * S_LEN;
#pragma unroll
    for (int i = 0; i < 4; ++i)
#pragma unroll
        for (int j = 0; j < 4; ++j)
#pragma unroll
            for (int r = 0; r < 4; ++r) {
                int gm = m0 + wm + i * 16 + quad * 4 + r;
                int gn = n0 + wn + j * 16 + l16;
                outb[(size_t)gm * S_LEN + gn] = acc[i][j][r] * scale;
            }
}

// -------- row softmax in place on d_out (fp32) + bf16 copy of P into ws --------
__global__ __launch_bounds__(256) void k_softmax(float* __restrict__ sc, u16* __restrict__ Pb) {
    __shared__ float red[4];
    const int row = blockIdx.x;
    float* sr = sc + (size_t)row * S_LEN;
    u16* pr = Pb + (size_t)row * S_LEN;
    const int tid = threadIdx.x, lane = tid & 63, w = tid >> 6;

    f32x4 v0 = *(const f32x4*)(sr + (size_t)tid * 4);
    f32x4 v1 = *(const f32x4*)(sr + (size_t)(tid + 256) * 4);

    float mx = fmaxf(fmaxf(fmaxf(v0.x, v0.y), fmaxf(v0.z, v0.w)),
                     fmaxf(fmaxf(v1.x, v1.y), fmaxf(v1.z, v1.w)));
#pragma unroll
    for (int off = 32; off > 0; off >>= 1) mx = fmaxf(mx, __shfl_xor(mx, off));
    if (lane == 0) red[w] = mx;
    __syncthreads();
    mx = fmaxf(fmaxf(red[0], red[1]), fmaxf(red[2], red[3]));
    __syncthreads();

    v0.x = expf(v0.x - mx); v0.y = expf(v0.y - mx); v0.z = expf(v0.z - mx); v0.w = expf(v0.w - mx);
    v1.x = expf(v1.x - mx); v1.y = expf(v1.y - mx); v1.z = expf(v1.z - mx); v1.w = expf(v1.w - mx);
    float sum = v0.x + v0.y + v0.z + v0.w + v1.x + v1.y + v1.z + v1.w;
#pragma unroll
    for (int off = 32; off > 0; off >>= 1) sum += __shfl_xor(sum, off);
    if (lane == 0) red[w] = sum;
    __syncthreads();
    sum = red[0] + red[1] + red[2] + red[3];
    float inv = 1.0f / sum;

    v0.x *= inv; v0.y *= inv; v0.z *= inv; v0.w *= inv;
    v1.x *= inv; v1.y *= inv; v1.z *= inv; v1.w *= inv;
    *(f32x4*)(sr + (size_t)tid * 4) = v0;
    *(f32x4*)(sr + (size_t)(tid + 256) * 4) = v1;
    ushort4 p0, p1;
    p0.x = f2bf(v0.x); p0.y = f2bf(v0.y); p0.z = f2bf(v0.z); p0.w = f2bf(v0.w);
    p1.x = f2bf(v1.x); p1.y = f2bf(v1.y); p1.z = f2bf(v1.z); p1.w = f2bf(v1.w);
    *(ushort4*)(pr + (size_t)tid * 4) = p0;
    *(ushort4*)(pr + (size_t)(tid + 256) * 4) = p1;
}

// -------- weighted = P * V  (A = P bf16 [2048x2048], B = V^T [512x2048]) --------
__global__ __launch_bounds__(256) void k_pv(const u16* __restrict__ Pb, const u16* __restrict__ VT,
                                            float* __restrict__ out) {
    __shared__ __align__(16) u16 lds[8192];
    const int b = blockIdx.z;
    const int m0 = blockIdx.y * 128, n0 = blockIdx.x * 128;
    const u16* A = Pb + (size_t)b * S_LEN * S_LEN + (size_t)m0 * S_LEN;
    const u16* B = VT + (size_t)b * DQ * S_LEN + (size_t)n0 * S_LEN;

    f32x4 acc[4][4];
#pragma unroll
    for (int i = 0; i < 4; ++i)
#pragma unroll
        for (int j = 0; j < 4; ++j) acc[i][j] = (f32x4)0.0f;

    int tid = threadIdx.x;
    gemm_core(A, B, S_LEN, acc, lds, lds + 4096, tid);

    const int lane = tid & 63, w = tid >> 6;
    const int wm = (w & 1) << 6, wn = (w >> 1) << 6;
    const int l16 = lane & 15, quad = lane >> 4;
    float* outb = out + (size_t)b * S_LEN * DQ;
#pragma unroll
    for (int i = 0; i < 4; ++i)
#pragma unroll
        for (int j = 0; j < 4; ++j)
#pragma unroll
            for (int r = 0; r < 4; ++r) {
                int gm = m0 + wm + i * 16 + quad * 4 + r;
                int gn = n0 + wn + j * 16 + l16;
                outb[(size_t)gm * DQ + gn] = acc[i][j][r];
            }
}

extern "C" void kernel_launch(void* const* d_in, const int* in_sizes, int n_in,
                              void* d_out, int out_size, void* d_ws, size_t ws_size,
                              hipStream_t stream) {
    const float* x  = (const float*)d_in[0];
    const float* Wq = (const float*)d_in[1];
    const float* bq = (const float*)d_in[2];
    const float* Wk = (const float*)d_in[3];
    const float* bk = (const float*)d_in[4];
    const float* Wv = (const float*)d_in[5];
    const float* bv = (const float*)d_in[6];

    char* ws = (char*)d_ws;
    u16* xb  = (u16*)(ws);                 // x bf16        [8192][512]   8.39 MB
    u16* Wb  = (u16*)(ws + 8388608);       // Wq,Wk,Wv bf16 3x[512][512]  1.57 MB
    u16* Qb  = (u16*)(ws + 9961472);       // Q bf16        [8192][512]
    u16* Kb  = (u16*)(ws + 18350080);      // K bf16        [8192][512]
    u16* Vb  = (u16*)(ws + 26738688);      // V bf16        [8192][512]
    u16* VTb = (u16*)(ws + 35127296);      // V^T bf16      [4][512][2048]
    u16* Pb  = (u16*)(ws + 43515904);      // P bf16        [8192][2048]  33.6 MB
    float* scores = (float*)d_out;                       // [4][2048][2048]
    float* wout   = (float*)d_out + 16777216;            // [4][2048][512]

    k_cvt<<<4096, 256, 0, stream>>>(x, xb, 1048576);
    k_cvt<<<256, 256, 0, stream>>>(Wq, Wb, 65536);
    k_cvt<<<256, 256, 0, stream>>>(Wk, Wb + 262144, 65536);
    k_cvt<<<256, 256, 0, stream>>>(Wv, Wb + 524288, 65536);

    k_proj<<<dim3(4, 64, 3), 256, 0, stream>>>(xb, Wb, bq, bk, bv, Qb);
    k_transpose<<<dim3(64, 16, 4), 256, 0, stream>>>(Vb, VTb);
    k_scores<<<dim3(16, 16, 4), 256, 0, stream>>>(Qb, Kb, scores);
    k_softmax<<<8192, 256, 0, stream>>>(scores, Pb);
    k_pv<<<dim3(4, 16, 4), 256, 0, stream>>>(Pb, VTb, wout);
}

// Round 2
// 225.700 us; speedup vs baseline: 1.0159x; 1.0159x over previous
//
#include <hip/hip_runtime.h>
#include <hip/hip_bf16.h>

typedef unsigned short u16;
typedef short bf16x8 __attribute__((ext_vector_type(8)));
typedef float f32x4 __attribute__((ext_vector_type(4)));

#define S_LEN 2048
#define DQ 512
#define NBATCH 4

__device__ __forceinline__ u16 f2bf(float f) {
    __hip_bfloat16 h = __float2bfloat16(f);
    return *reinterpret_cast<u16*>(&h);
}

__device__ __forceinline__ void async16(const u16* g, u16* l) {
    __builtin_amdgcn_global_load_lds(
        (__attribute__((address_space(1))) void*)g,
        (__attribute__((address_space(3))) void*)l, 16, 0, 0);
}

// -------- fp32 -> bf16 convert: x + Wq + Wk + Wv in one launch --------
// blocks [0,4096): x (1048576 vec4); [4096,4352): Wq; [4352,4608): Wk; [4608,4864): Wv
__global__ __launch_bounds__(256) void k_cvt_all(const float* __restrict__ x,
                                                 const float* __restrict__ wq,
                                                 const float* __restrict__ wk,
                                                 const float* __restrict__ wv,
                                                 u16* __restrict__ xb, u16* __restrict__ wb) {
    int bid = blockIdx.x;
    const float* src;
    u16* dst;
    int i;
    if (bid < 4096)      { src = x;  dst = xb;          i = bid * 256 + threadIdx.x; }
    else if (bid < 4352) { src = wq; dst = wb;          i = (bid - 4096) * 256 + threadIdx.x; }
    else if (bid < 4608) { src = wk; dst = wb + 262144; i = (bid - 4352) * 256 + threadIdx.x; }
    else                 { src = wv; dst = wb + 524288; i = (bid - 4608) * 256 + threadIdx.x; }
    f32x4 v = *(const f32x4*)(src + (size_t)i * 4);
    ushort4 o;
    o.x = f2bf(v.x); o.y = f2bf(v.y); o.z = f2bf(v.z); o.w = f2bf(v.w);
    *(ushort4*)(dst + (size_t)i * 4) = o;
}

// -------- shared 128x128 GEMM core: C += A[128 x krange] * B[128 x krange]^T --------
// A,B pre-offset to the block's first row; lda/ldb are row strides in elements.
__device__ __forceinline__ void gemm_core(const u16* __restrict__ A, const u16* __restrict__ B,
                                          int lda, int ldb, int kbeg, int kend,
                                          f32x4 acc[4][4], u16* ldsA, u16* ldsB, int tid) {
    const int lane = tid & 63;
    const int w    = tid >> 6;
    const int wm   = (w & 1) << 6;
    const int wn   = (w >> 1) << 6;
    const int l16  = lane & 15;
    const int quad = lane >> 4;

    for (int k0 = kbeg; k0 < kend; k0 += 32) {
        // stage A,B tiles (128 rows x 32 cols bf16 = 8 KB each) via direct-to-LDS 16B loads
#pragma unroll
        for (int i = 0; i < 2; ++i) {
            int c  = i * 256 + tid;        // chunk 0..511, 16B each
            int r  = c >> 2;               // row 0..127
            int cc = (c & 3) << 3;         // col element 0/8/16/24
            async16(A + (size_t)r * lda + k0 + cc, ldsA + r * 32 + cc);
            async16(B + (size_t)r * ldb + k0 + cc, ldsB + r * 32 + cc);
        }
        __syncthreads();
        bf16x8 af[4], bf[4];
#pragma unroll
        for (int i = 0; i < 4; ++i)
            af[i] = *(const bf16x8*)(ldsA + (wm + i * 16 + l16) * 32 + quad * 8);
#pragma unroll
        for (int j = 0; j < 4; ++j)
            bf[j] = *(const bf16x8*)(ldsB + (wn + j * 16 + l16) * 32 + quad * 8);
#pragma unroll
        for (int i = 0; i < 4; ++i)
#pragma unroll
            for (int j = 0; j < 4; ++j)
                acc[i][j] = __builtin_amdgcn_mfma_f32_16x16x32_bf16(af[i], bf[j], acc[i][j], 0, 0, 0);
        __syncthreads();
    }
}

// -------- projection: out(z) = x * W(z)^T + b(z), bf16 out; z in {Q,K,V} --------
__global__ __launch_bounds__(256) void k_proj(const u16* __restrict__ xb, const u16* __restrict__ Wb,
                                              const float* __restrict__ bq, const float* __restrict__ bk,
                                              const float* __restrict__ bv, u16* __restrict__ out) {
    __shared__ __align__(16) u16 lds[8192];
    const int z = blockIdx.z;
    const int m0 = blockIdx.y * 128, n0 = blockIdx.x * 128;
    const u16* A = xb + (size_t)m0 * DQ;
    const u16* B = Wb + (size_t)z * DQ * DQ + (size_t)n0 * DQ;
    const float* bias = (z == 0) ? bq : (z == 1) ? bk : bv;

    f32x4 acc[4][4];
#pragma unroll
    for (int i = 0; i < 4; ++i)
#pragma unroll
        for (int j = 0; j < 4; ++j) acc[i][j] = (f32x4)0.0f;

    int tid = threadIdx.x;
    gemm_core(A, B, DQ, DQ, 0, DQ, acc, lds, lds + 4096, tid);

    const int lane = tid & 63, w = tid >> 6;
    const int wm = (w & 1) << 6, wn = (w >> 1) << 6;
    const int l16 = lane & 15, quad = lane >> 4;
    u16* outz = out + (size_t)z * 8192 * DQ;
#pragma unroll
    for (int j = 0; j < 4; ++j) {
        int gn = n0 + wn + j * 16 + l16;
        float bb = bias[gn];
#pragma unroll
        for (int i = 0; i < 4; ++i)
#pragma unroll
            for (int r = 0; r < 4; ++r) {
                int gm = m0 + wm + i * 16 + quad * 4 + r;
                outz[(size_t)gm * DQ + gn] = f2bf(acc[i][j][r] + bb);
            }
    }
}

// -------- V [2048x512] -> V^T [512x2048] per batch --------
__global__ __launch_bounds__(256) void k_transpose(const u16* __restrict__ V, u16* __restrict__ VT) {
    __shared__ u16 tile[32][33];
    const int b = blockIdx.z;
    const int t0 = blockIdx.x * 32, d0 = blockIdx.y * 32;
    const u16* Vb_ = V + (size_t)b * S_LEN * DQ;
    u16* VTb_ = VT + (size_t)b * DQ * S_LEN;
    const int tx = threadIdx.x & 31, ty = threadIdx.x >> 5;
#pragma unroll
    for (int r = 0; r < 4; ++r)
        tile[ty + r * 8][tx] = Vb_[(size_t)(t0 + ty + r * 8) * DQ + d0 + tx];
    __syncthreads();
#pragma unroll
    for (int r = 0; r < 4; ++r)
        VTb_[(size_t)(d0 + ty + r * 8) * S_LEN + t0 + tx] = tile[tx][ty + r * 8];
}

// -------- scores = Q K^T * scale, fp32 raw into d_out --------
__global__ __launch_bounds__(256) void k_scores(const u16* __restrict__ Qb, const u16* __restrict__ Kb,
                                                float* __restrict__ out) {
    __shared__ __align__(16) u16 lds[8192];
    const int b = blockIdx.z;
    const int m0 = blockIdx.y * 128, n0 = blockIdx.x * 128;
    const u16* A = Qb + ((size_t)b * S_LEN + m0) * DQ;
    const u16* B = Kb + ((size_t)b * S_LEN + n0) * DQ;

    f32x4 acc[4][4];
#pragma unroll
    for (int i = 0; i < 4; ++i)
#pragma unroll
        for (int j = 0; j < 4; ++j) acc[i][j] = (f32x4)0.0f;

    int tid = threadIdx.x;
    gemm_core(A, B, DQ, DQ, 0, DQ, acc, lds, lds + 4096, tid);

    const float scale = 0.044194173824159216f; // 1/sqrt(512)
    const int lane = tid & 63, w = tid >> 6;
    const int wm = (w & 1) << 6, wn = (w >> 1) << 6;
    const int l16 = lane & 15, quad = lane >> 4;
    float* outb = out + (size_t)b * S_LEN * S_LEN;
#pragma unroll
    for (int i = 0; i < 4; ++i)
#pragma unroll
        for (int j = 0; j < 4; ++j)
#pragma unroll
            for (int r = 0; r < 4; ++r) {
                int gm = m0 + wm + i * 16 + quad * 4 + r;
                int gn = n0 + wn + j * 16 + l16;
                outb[(size_t)gm * S_LEN + gn] = acc[i][j][r] * scale;
            }
}

// -------- row softmax in place on d_out (fp32) + bf16 copy of P into ws --------
__global__ __launch_bounds__(256) void k_softmax(float* __restrict__ sc, u16* __restrict__ Pb) {
    __shared__ float red[4];
    const int row = blockIdx.x;
    float* sr = sc + (size_t)row * S_LEN;
    u16* pr = Pb + (size_t)row * S_LEN;
    const int tid = threadIdx.x, lane = tid & 63, w = tid >> 6;

    f32x4 v0 = *(const f32x4*)(sr + (size_t)tid * 4);
    f32x4 v1 = *(const f32x4*)(sr + (size_t)(tid + 256) * 4);

    float mx = fmaxf(fmaxf(fmaxf(v0.x, v0.y), fmaxf(v0.z, v0.w)),
                     fmaxf(fmaxf(v1.x, v1.y), fmaxf(v1.z, v1.w)));
#pragma unroll
    for (int off = 32; off > 0; off >>= 1) mx = fmaxf(mx, __shfl_xor(mx, off));
    if (lane == 0) red[w] = mx;
    __syncthreads();
    mx = fmaxf(fmaxf(red[0], red[1]), fmaxf(red[2], red[3]));
    __syncthreads();

    v0.x = expf(v0.x - mx); v0.y = expf(v0.y - mx); v0.z = expf(v0.z - mx); v0.w = expf(v0.w - mx);
    v1.x = expf(v1.x - mx); v1.y = expf(v1.y - mx); v1.z = expf(v1.z - mx); v1.w = expf(v1.w - mx);
    float sum = v0.x + v0.y + v0.z + v0.w + v1.x + v1.y + v1.z + v1.w;
#pragma unroll
    for (int off = 32; off > 0; off >>= 1) sum += __shfl_xor(sum, off);
    if (lane == 0) red[w] = sum;
    __syncthreads();
    sum = red[0] + red[1] + red[2] + red[3];
    float inv = 1.0f / sum;

    v0.x *= inv; v0.y *= inv; v0.z *= inv; v0.w *= inv;
    v1.x *= inv; v1.y *= inv; v1.z *= inv; v1.w *= inv;
    *(f32x4*)(sr + (size_t)tid * 4) = v0;
    *(f32x4*)(sr + (size_t)(tid + 256) * 4) = v1;
    ushort4 p0, p1;
    p0.x = f2bf(v0.x); p0.y = f2bf(v0.y); p0.z = f2bf(v0.z); p0.w = f2bf(v0.w);
    p1.x = f2bf(v1.x); p1.y = f2bf(v1.y); p1.z = f2bf(v1.z); p1.w = f2bf(v1.w);
    *(ushort4*)(pr + (size_t)tid * 4) = p0;
    *(ushort4*)(pr + (size_t)(tid + 256) * 4) = p1;
}

// -------- weighted = P * V, split-K=3 --------
// z = b*3 + slice; slice 0 -> wout, slices 1,2 -> partial buffers (reduced after).
// K slices: [0,704), [704,1376), [1376,2048)
__global__ __launch_bounds__(256) void k_pv(const u16* __restrict__ Pb, const u16* __restrict__ VT,
                                            float* __restrict__ wout, float* __restrict__ part) {
    __shared__ __align__(16) u16 lds[8192];
    const int bz = blockIdx.z;
    const int b = bz / 3, slice = bz - b * 3;
    const int m0 = blockIdx.y * 128, n0 = blockIdx.x * 128;
    const u16* A = Pb + (size_t)b * S_LEN * S_LEN + (size_t)m0 * S_LEN;
    const u16* B = VT + (size_t)b * DQ * S_LEN + (size_t)n0 * S_LEN;
    const int kbeg = (slice == 0) ? 0 : (slice == 1) ? 704 : 1376;
    const int kend = (slice == 0) ? 704 : (slice == 1) ? 1376 : 2048;

    f32x4 acc[4][4];
#pragma unroll
    for (int i = 0; i < 4; ++i)
#pragma unroll
        for (int j = 0; j < 4; ++j) acc[i][j] = (f32x4)0.0f;

    int tid = threadIdx.x;
    gemm_core(A, B, S_LEN, S_LEN, kbeg, kend, acc, lds, lds + 4096, tid);

    const int lane = tid & 63, w = tid >> 6;
    const int wm = (w & 1) << 6, wn = (w >> 1) << 6;
    const int l16 = lane & 15, quad = lane >> 4;
    float* outb = (slice == 0) ? (wout + (size_t)b * S_LEN * DQ)
                               : (part + (size_t)(slice - 1) * NBATCH * S_LEN * DQ
                                       + (size_t)b * S_LEN * DQ);
#pragma unroll
    for (int i = 0; i < 4; ++i)
#pragma unroll
        for (int j = 0; j < 4; ++j)
#pragma unroll
            for (int r = 0; r < 4; ++r) {
                int gm = m0 + wm + i * 16 + quad * 4 + r;
                int gn = n0 + wn + j * 16 + l16;
                outb[(size_t)gm * DQ + gn] = acc[i][j][r];
            }
}

// -------- wout += p1 + p2, vectorized x4 --------
__global__ __launch_bounds__(256) void k_reduce(float* __restrict__ wout,
                                                const float* __restrict__ part) {
    size_t i = (size_t)blockIdx.x * 256 + threadIdx.x;
    f32x4 a = *(const f32x4*)(wout + i * 4);
    f32x4 p1 = *(const f32x4*)(part + i * 4);
    f32x4 p2 = *(const f32x4*)(part + 4194304 + i * 4);
    a = a + p1 + p2;
    *(f32x4*)(wout + i * 4) = a;
}

extern "C" void kernel_launch(void* const* d_in, const int* in_sizes, int n_in,
                              void* d_out, int out_size, void* d_ws, size_t ws_size,
                              hipStream_t stream) {
    const float* x  = (const float*)d_in[0];
    const float* Wq = (const float*)d_in[1];
    const float* bq = (const float*)d_in[2];
    const float* Wk = (const float*)d_in[3];
    const float* bk = (const float*)d_in[4];
    const float* Wv = (const float*)d_in[5];
    const float* bv = (const float*)d_in[6];

    char* ws = (char*)d_ws;
    u16* xb  = (u16*)(ws);                 // x bf16        [8192][512]   8.39 MB
    u16* Wb  = (u16*)(ws + 8388608);       // Wq,Wk,Wv bf16 3x[512][512]  1.57 MB
    u16* Qb  = (u16*)(ws + 9961472);       // Q bf16        [8192][512]
    u16* Kb  = (u16*)(ws + 18350080);      // K bf16        [8192][512]
    u16* Vb  = (u16*)(ws + 26738688);      // V bf16        [8192][512]
    u16* VTb = (u16*)(ws + 35127296);      // V^T bf16      [4][512][2048]
    u16* Pb  = (u16*)(ws + 43515904);      // P bf16        [8192][2048]  33.6 MB
    // PV split-K partials reuse the (dead-by-then) xb/Wb/Qb/Kb/Vb region:
    float* pvpart = (float*)(ws);          // 2 x [4][2048][512] fp32 = 33.6 MB < 35.1 MB
    float* scores = (float*)d_out;                       // [4][2048][2048]
    float* wout   = (float*)d_out + 16777216;            // [4][2048][512]

    k_cvt_all<<<4864, 256, 0, stream>>>(x, Wq, Wk, Wv, xb, (u16*)(ws + 8388608));

    k_proj<<<dim3(4, 64, 3), 256, 0, stream>>>(xb, Wb, bq, bk, bv, Qb);
    k_transpose<<<dim3(64, 16, 4), 256, 0, stream>>>(Vb, VTb);
    k_scores<<<dim3(16, 16, 4), 256, 0, stream>>>(Qb, Kb, scores);
    k_softmax<<<8192, 256, 0, stream>>>(scores, Pb);
    k_pv<<<dim3(4, 16, 12), 256, 0, stream>>>(Pb, VTb, wout, pvpart);
    k_reduce<<<4096, 256, 0, stream>>>(wout, pvpart);
}